// Round 11
// baseline (1487.572 us; speedup 1.0000x reference)
//
#include <hip/hip_runtime.h>

#define B_ 16
#define N_ 4096
#define M_ 1024
#define S_ 32
#define IN_ 64
#define C0IN 67
#define C0 64
#define C1 64
#define C2 128
#define NTOT (B_*M_*S_)
#define R2 0.04f
#define CAP 1024
#define NBUCK 16
#define BQ_G 32
#define MCEN 16

#define FPS_T 256
#define FPS_PTS 16

// 64-bit DPP max (packed key).
#define DPP_U64_MAX(k, ctrl) { \
    unsigned int _lo = (unsigned int)(k), _hi = (unsigned int)((k) >> 32); \
    unsigned int _olo = (unsigned int)__builtin_amdgcn_update_dpp((int)_lo, (int)_lo, ctrl, 0xF, 0xF, false); \
    unsigned int _ohi = (unsigned int)__builtin_amdgcn_update_dpp((int)_hi, (int)_hi, ctrl, 0xF, 0xF, false); \
    unsigned long long _o = ((unsigned long long)_ohi << 32) | _olo; \
    if (_o > (k)) (k) = _o; }

// ---------------- FPS ---------------- (frozen, proven 662-667 us)
__global__ __launch_bounds__(FPS_T, 1) void fps_kernel(const float* __restrict__ xyz,
                                                       int* __restrict__ fps_idx,
                                                       float* __restrict__ out_xyz) {
#pragma clang fp contract(off)
    __shared__ float4 pxyz[N_];
    __shared__ int    sel[M_];
    __shared__ __align__(16) unsigned long long slotk[2][4];
    int b = blockIdx.x, t = threadIdx.x;
    const float* xb = xyz + (size_t)b * N_ * 3;
    float lx[FPS_PTS], ly[FPS_PTS], lz[FPS_PTS], dl[FPS_PTS];
#pragma unroll
    for (int j = 0; j < FPS_PTS; j++) {
        int i = (j << 8) + t;
        float x = xb[3*i], y = xb[3*i+1], z = xb[3*i+2];
        lx[j] = x; ly[j] = y; lz[j] = z;
        dl[j] = __builtin_inff();
        pxyz[i] = make_float4(x, y, z, 0.f);
    }
    __syncthreads();
    int wid = t >> 6, lane = t & 63;
    int cur = 0;
    float4 cc = pxyz[0];
    for (int k = 0; k < M_; k++) {
        float cx = cc.x, cy = cc.y, cz = cc.z;
        if (t == 0) sel[k] = cur;
#pragma unroll
        for (int j = 0; j < FPS_PTS; j++)
            asm volatile("" : "+v"(lx[j]), "+v"(ly[j]), "+v"(lz[j]));
        float bv = -1.0f; int bi = 0x7fffffff;
#pragma unroll
        for (int j = 0; j < FPS_PTS; j++) {
            float dx = lx[j] - cx, dy = ly[j] - cy, dz = lz[j] - cz;
            float t0 = dx*dx, t1 = dy*dy, t2 = dz*dz;
            float d = (t0 + t1) + t2;
            float od = dl[j];
            float nd = d < od ? d : od;
            dl[j] = nd;
            if (nd > bv) { bv = nd; bi = (j << 8) + t; }
        }
        unsigned long long key = ((unsigned long long)__float_as_uint(bv) << 32)
                               | (unsigned int)(~bi);
        DPP_U64_MAX(key, 0x111);
        DPP_U64_MAX(key, 0x112);
        DPP_U64_MAX(key, 0x114);
        DPP_U64_MAX(key, 0x118);
        DPP_U64_MAX(key, 0x142);
        DPP_U64_MAX(key, 0x143);
        int p = k & 1;
        if (lane == 63) slotk[p][wid] = key;
        __syncthreads();
        ulonglong2 s01 = *(const ulonglong2*)&slotk[p][0];
        ulonglong2 s23 = *(const ulonglong2*)&slotk[p][2];
        unsigned long long kk = s01.x;
        if (s01.y > kk) kk = s01.y;
        if (s23.x > kk) kk = s23.x;
        if (s23.y > kk) kk = s23.y;
        cur = (int)(~(unsigned int)kk);
        cc = pxyz[cur];
    }
    __syncthreads();
    for (int i = t; i < M_; i += FPS_T) {
        int ix = sel[i];
        float4 q = pxyz[ix];
        fps_idx[b*M_ + i] = ix;
        out_xyz[(b*M_ + i)*3 + 0] = q.x;
        out_xyz[(b*M_ + i)*3 + 1] = q.y;
        out_xyz[(b*M_ + i)*3 + 2] = q.z;
    }
}

// ---------------- Ball query (grouped, frozen) ----------------
__global__ __launch_bounds__(256) void ballq_kernel(const float* __restrict__ xyz,
                                                    const int* __restrict__ fps_idx,
                                                    int* __restrict__ ball_idx) {
#pragma clang fp contract(off)
    __shared__ float4 pts[N_];
    __shared__ float cd[CAP];
    __shared__ int   ci[CAP];
    __shared__ int   cnt;
    __shared__ float rv[4];
    __shared__ int   ri[4];
    __shared__ int   slots[33];
    int blk = blockIdx.x;
    int b = blk >> 5;
    int g = blk & 31;
    int t = threadIdx.x;
    const float* xb = xyz + (size_t)b * N_ * 3;
    for (int i = t; i < N_; i += 256)
        pts[i] = make_float4(xb[i*3+0], xb[i*3+1], xb[i*3+2], 0.f);
    __syncthreads();
    for (int mm = 0; mm < BQ_G; mm++) {
        int m = (g << 5) + mm;
        if (t == 0) cnt = 0;
        __syncthreads();
        float4 c4 = pts[fps_idx[b*M_ + m]];
        float cx = c4.x, cy = c4.y, cz = c4.z;
        float bv = 3.4e38f; int bi = 0x7fffffff;
        for (int i = t; i < N_; i += 256) {
            float4 p = pts[i];
            float dx = p.x - cx, dy = p.y - cy, dz = p.z - cz;
            float t0 = dx*dx, t1 = dy*dy, t2 = dz*dz;
            float d = (t0 + t1) + t2;
            if (d < bv || (d == bv && i < bi)) { bv = d; bi = i; }
            if (d <= R2) {
                int pp = atomicAdd(&cnt, 1);
                if (pp < CAP) { cd[pp] = d; ci[pp] = i; }
            }
        }
        for (int off = 32; off >= 1; off >>= 1) {
            float ov = __shfl_xor(bv, off, 64);
            int   oi = __shfl_xor(bi, off, 64);
            if (ov < bv || (ov == bv && oi < bi)) { bv = ov; bi = oi; }
        }
        int w = t >> 6;
        if ((t & 63) == 0) { rv[w] = bv; ri[w] = bi; }
        __syncthreads();
        int n = cnt < CAP ? cnt : CAP;
        for (int j = t; j < n; j += 256) {
            float dj = cd[j]; int ij = ci[j];
            int rank = 0;
            for (int k = 0; k < n; k++) {
                float dk = cd[k]; int ik = ci[k];
                rank += (dk < dj) || (dk == dj && ik < ij);
            }
            if (rank < S_) slots[rank] = ij;
        }
        if (t == 0) {
            float v = rv[0]; int ix = ri[0];
            for (int j = 1; j < 4; j++)
                if (rv[j] < v || (rv[j] == v && ri[j] < ix)) { v = rv[j]; ix = ri[j]; }
            slots[32] = ix;
        }
        __syncthreads();
        if (t < S_) {
            int nearest = (n > 0) ? slots[0] : slots[32];
            int ix = (t < n) ? slots[t] : nearest;
            ball_idx[(size_t)(b*M_ + m)*S_ + t] = ix;
        }
    }
}

// ============ Staged pipeline, MCEN centers per block ============
// NEW this round: (a) S3 emits per-center per-channel (zmax,zmin) instead of
// the full 32-sample z2 (monotonicity: max_s relu(a*z+c) == relu(a*zmax+c) for
// a>0, relu(a*zmin+c) for a<0 -- BIT-EXACT, IEEE mult/add monotone, equality
// attained at the extremal sample; a==0 gives identical stored bits).
// (b) BN stage loads z as float4 (4x fewer load + LDS-write instrs).

// S1: gather + L0 -> z0, stats0 (unchanged from round 10)
__global__ __launch_bounds__(256) void mlpS1_kernel(
    const float* __restrict__ xyz, const float* __restrict__ feat,
    const int* __restrict__ fps_idx, const int* __restrict__ ball_idx,
    const float* __restrict__ w0, const float* __restrict__ b0,
    float* __restrict__ zbuf, float* __restrict__ stats) {
    __shared__ __align__(16) float xs[S_][72];
    __shared__ float rsum[64][9], rsq[64][9];
    __shared__ int idxs[S_];
    int blk0 = blockIdx.x * MCEN, t = threadIdx.x;
    int b = blk0 >> 10;
    const float* xb = xyz + (size_t)b * N_ * 3;
    int dp = t & 31, sg = t >> 5;
    int d0 = dp * 2;
    float wA[72], wB[72];
    {
        const float* wa = w0 + (size_t)d0 * C0IN;
        const float* wb = wa + C0IN;
        wA[0] = wa[0]; wA[1] = wa[1]; wA[2] = wa[2]; wA[3] = 0.f;
        wB[0] = wb[0]; wB[1] = wb[1]; wB[2] = wb[2]; wB[3] = 0.f;
#pragma unroll
        for (int c = 0; c < 64; c++) { wA[4 + c] = wa[3 + c]; wB[4 + c] = wb[3 + c]; }
#pragma unroll
        for (int c = 68; c < 72; c++) { wA[c] = 0.f; wB[c] = 0.f; }
    }
    float bi0 = b0[d0], bi1 = b0[d0+1];
    if (t < 32) { xs[t][3] = 0.f; }
    else if (t < 160) { int s = (t - 32) >> 2; xs[s][68 + ((t - 32) & 3)] = 0.f; }
    float ls0 = 0.f, lq0 = 0.f, ls1 = 0.f, lq1 = 0.f;
    for (int e = 0; e < MCEN; e++) {
        int blk = blk0 + e;
        int m = blk & (M_ - 1);
        int cidx = fps_idx[b*M_ + m];
        float cx = xb[cidx*3+0], cy = xb[cidx*3+1], cz = xb[cidx*3+2];
        if (t < S_) idxs[t] = ball_idx[(size_t)blk * S_ + t];
        __syncthreads();
#pragma unroll
        for (int ii = 0; ii < 2; ii++) {
            int i = t + ii * 256;
            int s = i >> 4, c4 = i & 15;
            int p = idxs[s];
            float4 v = *(const float4*)&feat[((size_t)b*N_ + p)*IN_ + 4*c4];
            *(float4*)&xs[s][4 + 4*c4] = v;
        }
        if (t < 96) {
            int s = t >> 2, comp = t & 3;
            if (comp < 3) {
                int p = idxs[s];
                float v = (comp == 0) ? xb[p*3+0] - cx
                        : (comp == 1) ? xb[p*3+1] - cy
                                      : xb[p*3+2] - cz;
                xs[s][comp] = v;
            }
        } else if (t < 224) {
            int tt = t - 96;
            int s = 24 + (tt >> 2), comp = tt & 3;
            if (comp < 3 && s < 32) {
                int p = idxs[s];
                float v = (comp == 0) ? xb[p*3+0] - cx
                        : (comp == 1) ? xb[p*3+1] - cy
                                      : xb[p*3+2] - cz;
                xs[s][comp] = v;
            }
        }
        __syncthreads();
        float acc0[4], acc1[4];
#pragma unroll
        for (int q = 0; q < 4; q++) { acc0[q] = bi0; acc1[q] = bi1; }
#pragma unroll
        for (int q = 0; q < 4; q++) {
            const float4* x4 = (const float4*)&xs[sg*4 + q][0];
#pragma unroll
            for (int c4 = 0; c4 < 18; c4++) {
                float4 v = x4[c4];
                acc0[q] += v.x * wA[4*c4+0]; acc1[q] += v.x * wB[4*c4+0];
                acc0[q] += v.y * wA[4*c4+1]; acc1[q] += v.y * wB[4*c4+1];
                acc0[q] += v.z * wA[4*c4+2]; acc1[q] += v.z * wB[4*c4+2];
                acc0[q] += v.w * wA[4*c4+3]; acc1[q] += v.w * wB[4*c4+3];
            }
        }
        float* zt = zbuf + (size_t)blk * 2048;
#pragma unroll
        for (int q = 0; q < 4; q++) {
            int s = sg*4 + q;
            *(float2*)&zt[s*64 + d0] = make_float2(acc0[q], acc1[q]);
            ls0 += acc0[q]; lq0 += acc0[q]*acc0[q];
            ls1 += acc1[q]; lq1 += acc1[q]*acc1[q];
        }
    }
    rsum[d0][sg] = ls0; rsq[d0][sg] = lq0;
    rsum[d0+1][sg] = ls1; rsq[d0+1][sg] = lq1;
    __syncthreads();
    if (t < 64) {
        float s = 0.f, s2 = 0.f;
#pragma unroll
        for (int j = 0; j < 8; j++) { s += rsum[t][j]; s2 += rsq[t][j]; }
        float* sb = stats + (size_t)(blockIdx.x & (NBUCK-1)) * 512;
        atomicAdd(&sb[t], s);
        atomicAdd(&sb[64 + t], s2);
    }
}

// S2: z0 -> BN0+relu -> L1 -> z1 (in-place), stats1. float4 z loads.
__global__ __launch_bounds__(256) void mlpS2_kernel(
    float* __restrict__ zbuf,
    const float* __restrict__ w1, const float* __restrict__ b1,
    const float* __restrict__ g0, const float* __restrict__ be0,
    float* __restrict__ stats) {
    __shared__ __align__(16) float y0s[S_][C0];
    __shared__ float rsum[64][9], rsq[64][9];
    __shared__ __align__(16) float lc[128];
    int blk0 = blockIdx.x * MCEN, t = threadIdx.x;
    const float inv_n = 1.0f / (float)NTOT;
    if (t < 64) {
        float s = 0.f, s2 = 0.f;
        for (int j = 0; j < NBUCK; j++) { s += stats[j*512 + t]; s2 += stats[j*512 + 64 + t]; }
        float mean = s * inv_n, var = s2 * inv_n - mean * mean;
        float a = g0[t] * (1.0f / sqrtf(var + 1e-5f));
        lc[t] = a; lc[64 + t] = be0[t] - mean * a;
    }
    int dv = (4*t) & 63;        // BN-stage channel base (4-aligned)
    int dp = t & 31, sg = t >> 5;
    int d0 = dp * 2;
    float wA[64], wB[64];
    {
        const float4* wa4 = (const float4*)(w1 + (size_t)d0 * C0);
        const float4* wb4 = (const float4*)(w1 + (size_t)(d0+1) * C0);
#pragma unroll
        for (int c4 = 0; c4 < 16; c4++) {
            float4 a = wa4[c4], bb = wb4[c4];
            wA[4*c4+0] = a.x;  wA[4*c4+1] = a.y;  wA[4*c4+2] = a.z;  wA[4*c4+3] = a.w;
            wB[4*c4+0] = bb.x; wB[4*c4+1] = bb.y; wB[4*c4+2] = bb.z; wB[4*c4+3] = bb.w;
        }
    }
    float bi0 = b1[d0], bi1 = b1[d0+1];
    __syncthreads();   // lc ready
    float4 av = *(const float4*)&lc[dv];
    float4 cv = *(const float4*)&lc[64 + dv];
    float ls0 = 0.f, lq0 = 0.f, ls1 = 0.f, lq1 = 0.f;
    for (int e = 0; e < MCEN; e++) {
        int blk = blk0 + e;
        float* zt = zbuf + (size_t)blk * 2048;
        float4 zv0 = *(const float4*)&zt[4*t];
        float4 zv1 = *(const float4*)&zt[4*t + 1024];
        if (e) __syncthreads();              // y0s reuse guard
        {
            int s0 = (4*t) >> 6, s1 = s0 + 16;
            float4 y0, y1;
            y0.x = zv0.x*av.x + cv.x; y0.y = zv0.y*av.y + cv.y;
            y0.z = zv0.z*av.z + cv.z; y0.w = zv0.w*av.w + cv.w;
            y1.x = zv1.x*av.x + cv.x; y1.y = zv1.y*av.y + cv.y;
            y1.z = zv1.z*av.z + cv.z; y1.w = zv1.w*av.w + cv.w;
            y0.x = y0.x > 0.f ? y0.x : 0.f; y0.y = y0.y > 0.f ? y0.y : 0.f;
            y0.z = y0.z > 0.f ? y0.z : 0.f; y0.w = y0.w > 0.f ? y0.w : 0.f;
            y1.x = y1.x > 0.f ? y1.x : 0.f; y1.y = y1.y > 0.f ? y1.y : 0.f;
            y1.z = y1.z > 0.f ? y1.z : 0.f; y1.w = y1.w > 0.f ? y1.w : 0.f;
            *(float4*)&y0s[s0][dv] = y0;
            *(float4*)&y0s[s1][dv] = y1;
        }
        __syncthreads();                     // y0s ready
        float acc0[4], acc1[4];
#pragma unroll
        for (int q = 0; q < 4; q++) { acc0[q] = bi0; acc1[q] = bi1; }
#pragma unroll
        for (int q = 0; q < 4; q++) {
            const float4* x4 = (const float4*)&y0s[sg*4 + q][0];
#pragma unroll
            for (int c4 = 0; c4 < 16; c4++) {
                float4 v = x4[c4];
                acc0[q] += v.x * wA[4*c4+0]; acc1[q] += v.x * wB[4*c4+0];
                acc0[q] += v.y * wA[4*c4+1]; acc1[q] += v.y * wB[4*c4+1];
                acc0[q] += v.z * wA[4*c4+2]; acc1[q] += v.z * wB[4*c4+2];
                acc0[q] += v.w * wA[4*c4+3]; acc1[q] += v.w * wB[4*c4+3];
            }
        }
#pragma unroll
        for (int q = 0; q < 4; q++) {
            int s = sg*4 + q;
            *(float2*)&zt[s*64 + d0] = make_float2(acc0[q], acc1[q]);
            ls0 += acc0[q]; lq0 += acc0[q]*acc0[q];
            ls1 += acc1[q]; lq1 += acc1[q]*acc1[q];
        }
    }
    rsum[d0][sg] = ls0; rsq[d0][sg] = lq0;
    rsum[d0+1][sg] = ls1; rsq[d0+1][sg] = lq1;
    __syncthreads();
    if (t < 64) {
        float s = 0.f, s2 = 0.f;
#pragma unroll
        for (int j = 0; j < 8; j++) { s += rsum[t][j]; s2 += rsq[t][j]; }
        float* sb = stats + (size_t)(blockIdx.x & (NBUCK-1)) * 512;
        atomicAdd(&sb[128 + t], s);
        atomicAdd(&sb[192 + t], s2);
    }
}

// S3: z1 -> BN1+relu -> L2 -> stats2 (+ per-center zmax/zmin when STOREMM)
template<int STOREMM>
__global__ __launch_bounds__(256) void mlpS3_kernel(
    const float* __restrict__ zbuf,
    const float* __restrict__ w2, const float* __restrict__ b2,
    const float* __restrict__ g1, const float* __restrict__ be1,
    float* __restrict__ mmbuf, float* __restrict__ stats) {
    __shared__ __align__(16) float y1s[S_][C1];
    __shared__ float rsum[128][5], rsq[128][5];
    __shared__ float rmx[128][5], rmn[128][5];
    __shared__ __align__(16) float lc[128];
    int blk0 = blockIdx.x * MCEN, t = threadIdx.x;
    const float inv_n = 1.0f / (float)NTOT;
    if (t < 64) {
        float s = 0.f, s2 = 0.f;
        for (int j = 0; j < NBUCK; j++) { s += stats[j*512 + 128 + t]; s2 += stats[j*512 + 192 + t]; }
        float mean = s * inv_n, var = s2 * inv_n - mean * mean;
        float a = g1[t] * (1.0f / sqrtf(var + 1e-5f));
        lc[t] = a; lc[64 + t] = be1[t] - mean * a;
    }
    int dv = (4*t) & 63;
    int dp = t & 63, sg = t >> 6;
    int d0 = dp * 2;
    float wA[64], wB[64];
    {
        const float4* wa4 = (const float4*)(w2 + (size_t)d0 * C1);
        const float4* wb4 = (const float4*)(w2 + (size_t)(d0+1) * C1);
#pragma unroll
        for (int c4 = 0; c4 < 16; c4++) {
            float4 a = wa4[c4], bb = wb4[c4];
            wA[4*c4+0] = a.x;  wA[4*c4+1] = a.y;  wA[4*c4+2] = a.z;  wA[4*c4+3] = a.w;
            wB[4*c4+0] = bb.x; wB[4*c4+1] = bb.y; wB[4*c4+2] = bb.z; wB[4*c4+3] = bb.w;
        }
    }
    float bi0 = b2[d0], bi1 = b2[d0+1];
    __syncthreads();   // lc ready
    float4 av = *(const float4*)&lc[dv];
    float4 cv = *(const float4*)&lc[64 + dv];
    float ls0 = 0.f, lq0 = 0.f, ls1 = 0.f, lq1 = 0.f;
    for (int e = 0; e < MCEN; e++) {
        int blk = blk0 + e;
        const float* zt = zbuf + (size_t)blk * 2048;
        float4 zv0 = *(const float4*)&zt[4*t];
        float4 zv1 = *(const float4*)&zt[4*t + 1024];
        if (e) __syncthreads();              // y1s reuse guard
        {
            int s0 = (4*t) >> 6, s1 = s0 + 16;
            float4 y0, y1;
            y0.x = zv0.x*av.x + cv.x; y0.y = zv0.y*av.y + cv.y;
            y0.z = zv0.z*av.z + cv.z; y0.w = zv0.w*av.w + cv.w;
            y1.x = zv1.x*av.x + cv.x; y1.y = zv1.y*av.y + cv.y;
            y1.z = zv1.z*av.z + cv.z; y1.w = zv1.w*av.w + cv.w;
            y0.x = y0.x > 0.f ? y0.x : 0.f; y0.y = y0.y > 0.f ? y0.y : 0.f;
            y0.z = y0.z > 0.f ? y0.z : 0.f; y0.w = y0.w > 0.f ? y0.w : 0.f;
            y1.x = y1.x > 0.f ? y1.x : 0.f; y1.y = y1.y > 0.f ? y1.y : 0.f;
            y1.z = y1.z > 0.f ? y1.z : 0.f; y1.w = y1.w > 0.f ? y1.w : 0.f;
            *(float4*)&y1s[s0][dv] = y0;
            *(float4*)&y1s[s1][dv] = y1;
        }
        __syncthreads();                     // y1s ready
        float acc0[8], acc1[8];
#pragma unroll
        for (int q = 0; q < 8; q++) { acc0[q] = bi0; acc1[q] = bi1; }
#pragma unroll
        for (int q = 0; q < 8; q++) {
            const float4* x4 = (const float4*)&y1s[sg*8 + q][0];
#pragma unroll
            for (int c4 = 0; c4 < 16; c4++) {
                float4 v = x4[c4];
                acc0[q] += v.x * wA[4*c4+0]; acc1[q] += v.x * wB[4*c4+0];
                acc0[q] += v.y * wA[4*c4+1]; acc1[q] += v.y * wB[4*c4+1];
                acc0[q] += v.z * wA[4*c4+2]; acc1[q] += v.z * wB[4*c4+2];
                acc0[q] += v.w * wA[4*c4+3]; acc1[q] += v.w * wB[4*c4+3];
            }
        }
#pragma unroll
        for (int q = 0; q < 8; q++) {
            ls0 += acc0[q]; lq0 += acc0[q]*acc0[q];
            ls1 += acc1[q]; lq1 += acc1[q]*acc1[q];
        }
        if (STOREMM) {
            float m0 = acc0[0], n0 = acc0[0], m1 = acc1[0], n1 = acc1[0];
#pragma unroll
            for (int q = 1; q < 8; q++) {
                m0 = acc0[q] > m0 ? acc0[q] : m0;  n0 = acc0[q] < n0 ? acc0[q] : n0;
                m1 = acc1[q] > m1 ? acc1[q] : m1;  n1 = acc1[q] < n1 ? acc1[q] : n1;
            }
            rmx[d0][sg] = m0; rmn[d0][sg] = n0;
            rmx[d0+1][sg] = m1; rmn[d0+1][sg] = n1;
            __syncthreads();                 // minmax ready
            if (t < 128) {
                float mx = rmx[t][0], mn = rmn[t][0];
#pragma unroll
                for (int j = 1; j < 4; j++) {
                    mx = rmx[t][j] > mx ? rmx[t][j] : mx;
                    mn = rmn[t][j] < mn ? rmn[t][j] : mn;
                }
                mmbuf[(size_t)blk * 256 + t] = mx;
                mmbuf[(size_t)blk * 256 + 128 + t] = mn;
            }
        }
    }
    rsum[d0][sg] = ls0; rsq[d0][sg] = lq0;
    rsum[d0+1][sg] = ls1; rsq[d0+1][sg] = lq1;
    __syncthreads();
    if (t < 128) {
        float s = 0.f, s2 = 0.f;
#pragma unroll
        for (int j = 0; j < 4; j++) { s += rsum[t][j]; s2 += rsq[t][j]; }
        float* sb = stats + (size_t)(blockIdx.x & (NBUCK-1)) * 512;
        atomicAdd(&sb[256 + t], s);
        atomicAdd(&sb[384 + t], s2);
    }
}

// S4m: out[cen][d] = relu(a * (a>0 ? zmax : zmin) + c)  — bit-exact vs
// max over samples (monotonicity; see header comment).
__global__ __launch_bounds__(256) void mlpS4m_kernel(
    const float* __restrict__ mmbuf,
    const float* __restrict__ g2, const float* __restrict__ be2,
    const float* __restrict__ stats, float* __restrict__ out_feat) {
    __shared__ float lc[256];
    int blk = blockIdx.x, t = threadIdx.x;
    const float inv_n = 1.0f / (float)NTOT;
    if (t < 128) {
        float s = 0.f, s2 = 0.f;
        for (int j = 0; j < NBUCK; j++) { s += stats[j*512 + 256 + t]; s2 += stats[j*512 + 384 + t]; }
        float mean = s * inv_n, var = s2 * inv_n - mean * mean;
        float a = g2[t] * (1.0f / sqrtf(var + 1e-5f));
        lc[t] = a; lc[128 + t] = be2[t] - mean * a;
    }
    __syncthreads();
    size_t base = (size_t)blk * 4096;   // 512 blocks x 4096 outputs
    for (int i = t; i < 4096; i += 256) {
        size_t gi = base + i;
        int cen = (int)(gi >> 7), d = (int)(gi & 127);
        float a = lc[d], c = lc[128 + d];
        float z = (a > 0.f) ? mmbuf[(size_t)cen*256 + d] : mmbuf[(size_t)cen*256 + 128 + d];
        float v = a * z + c;
        out_feat[gi] = v > 0.f ? v : 0.f;
    }
}

// S4r: recompute fallback (ws too small for mm): z1 -> BN1+relu -> L2 -> BN2+relu -> max
__global__ __launch_bounds__(256) void mlpS4r_kernel(
    const float* __restrict__ zbuf,
    const float* __restrict__ w2, const float* __restrict__ b2,
    const float* __restrict__ g1, const float* __restrict__ be1,
    const float* __restrict__ g2, const float* __restrict__ be2,
    const float* __restrict__ stats, float* __restrict__ out_feat) {
    __shared__ __align__(16) float y1s[S_][C1];
    __shared__ float rmax[128][5];
    __shared__ __align__(16) float lc[384];
    int blk0 = blockIdx.x * MCEN, t = threadIdx.x;
    const float inv_n = 1.0f / (float)NTOT;
    if (t < 64) {
        float s = 0.f, s2 = 0.f;
        for (int j = 0; j < NBUCK; j++) { s += stats[j*512 + 128 + t]; s2 += stats[j*512 + 192 + t]; }
        float mean = s * inv_n, var = s2 * inv_n - mean * mean;
        float a = g1[t] * (1.0f / sqrtf(var + 1e-5f));
        lc[t] = a; lc[64 + t] = be1[t] - mean * a;
    }
    if (t < 128) {
        float s = 0.f, s2 = 0.f;
        for (int j = 0; j < NBUCK; j++) { s += stats[j*512 + 256 + t]; s2 += stats[j*512 + 384 + t]; }
        float mean = s * inv_n, var = s2 * inv_n - mean * mean;
        float a = g2[t] * (1.0f / sqrtf(var + 1e-5f));
        lc[128 + t] = a; lc[256 + t] = be2[t] - mean * a;
    }
    int dv = (4*t) & 63;
    int dp = t & 63, sg = t >> 6;
    int d0 = dp * 2;
    float wA[64], wB[64];
    {
        const float4* wa4 = (const float4*)(w2 + (size_t)d0 * C1);
        const float4* wb4 = (const float4*)(w2 + (size_t)(d0+1) * C1);
#pragma unroll
        for (int c4 = 0; c4 < 16; c4++) {
            float4 a = wa4[c4], bb = wb4[c4];
            wA[4*c4+0] = a.x;  wA[4*c4+1] = a.y;  wA[4*c4+2] = a.z;  wA[4*c4+3] = a.w;
            wB[4*c4+0] = bb.x; wB[4*c4+1] = bb.y; wB[4*c4+2] = bb.z; wB[4*c4+3] = bb.w;
        }
    }
    float bi0 = b2[d0], bi1 = b2[d0+1];
    __syncthreads();   // lc ready
    float4 av = *(const float4*)&lc[dv];
    float4 cvv = *(const float4*)&lc[64 + dv];
    float a20 = lc[128 + d0], c20 = lc[256 + d0];
    float a21 = lc[128 + d0 + 1], c21 = lc[256 + d0 + 1];
    for (int e = 0; e < MCEN; e++) {
        int blk = blk0 + e;
        const float* zt = zbuf + (size_t)blk * 2048;
        float4 zv0 = *(const float4*)&zt[4*t];
        float4 zv1 = *(const float4*)&zt[4*t + 1024];
        if (e) __syncthreads();              // y1s/rmax reuse guard
        {
            int s0 = (4*t) >> 6, s1 = s0 + 16;
            float4 y0, y1;
            y0.x = zv0.x*av.x + cvv.x; y0.y = zv0.y*av.y + cvv.y;
            y0.z = zv0.z*av.z + cvv.z; y0.w = zv0.w*av.w + cvv.w;
            y1.x = zv1.x*av.x + cvv.x; y1.y = zv1.y*av.y + cvv.y;
            y1.z = zv1.z*av.z + cvv.z; y1.w = zv1.w*av.w + cvv.w;
            y0.x = y0.x > 0.f ? y0.x : 0.f; y0.y = y0.y > 0.f ? y0.y : 0.f;
            y0.z = y0.z > 0.f ? y0.z : 0.f; y0.w = y0.w > 0.f ? y0.w : 0.f;
            y1.x = y1.x > 0.f ? y1.x : 0.f; y1.y = y1.y > 0.f ? y1.y : 0.f;
            y1.z = y1.z > 0.f ? y1.z : 0.f; y1.w = y1.w > 0.f ? y1.w : 0.f;
            *(float4*)&y1s[s0][dv] = y0;
            *(float4*)&y1s[s1][dv] = y1;
        }
        __syncthreads();                     // y1s ready
        float acc0[8], acc1[8];
#pragma unroll
        for (int q = 0; q < 8; q++) { acc0[q] = bi0; acc1[q] = bi1; }
#pragma unroll
        for (int q = 0; q < 8; q++) {
            const float4* x4 = (const float4*)&y1s[sg*8 + q][0];
#pragma unroll
            for (int c4 = 0; c4 < 16; c4++) {
                float4 v = x4[c4];
                acc0[q] += v.x * wA[4*c4+0]; acc1[q] += v.x * wB[4*c4+0];
                acc0[q] += v.y * wA[4*c4+1]; acc1[q] += v.y * wB[4*c4+1];
                acc0[q] += v.z * wA[4*c4+2]; acc1[q] += v.z * wB[4*c4+2];
                acc0[q] += v.w * wA[4*c4+3]; acc1[q] += v.w * wB[4*c4+3];
            }
        }
        float lm0 = -3.4e38f, lm1 = -3.4e38f;
#pragma unroll
        for (int q = 0; q < 8; q++) {
            float v0 = acc0[q] * a20 + c20; v0 = v0 > 0.f ? v0 : 0.f;
            float v1 = acc1[q] * a21 + c21; v1 = v1 > 0.f ? v1 : 0.f;
            lm0 = v0 > lm0 ? v0 : lm0;
            lm1 = v1 > lm1 ? v1 : lm1;
        }
        rmax[d0][sg] = lm0; rmax[d0+1][sg] = lm1;
        __syncthreads();                     // rmax ready
        if (t < 128) {
            float v = rmax[t][0];
#pragma unroll
            for (int j = 1; j < 4; j++) v = rmax[t][j] > v ? rmax[t][j] : v;
            out_feat[(size_t)blk * C2 + t] = v;
        }
    }
}

extern "C" void kernel_launch(void* const* d_in, const int* in_sizes, int n_in,
                              void* d_out, int out_size, void* d_ws, size_t ws_size,
                              hipStream_t stream) {
    const float* xyz  = (const float*)d_in[0];
    const float* feat = (const float*)d_in[1];
    const float* w0 = (const float*)d_in[2];  const float* b0 = (const float*)d_in[3];
    const float* g0 = (const float*)d_in[4];  const float* be0 = (const float*)d_in[5];
    const float* w1 = (const float*)d_in[6];  const float* b1 = (const float*)d_in[7];
    const float* g1 = (const float*)d_in[8];  const float* be1 = (const float*)d_in[9];
    const float* w2 = (const float*)d_in[10]; const float* b2 = (const float*)d_in[11];
    const float* g2 = (const float*)d_in[12]; const float* be2 = (const float*)d_in[13];
    float* out_xyz  = (float*)d_out;
    float* out_feat = out_xyz + B_*M_*3;

    int* fps_i  = (int*)d_ws;                                   // 64 KB
    int* ball_i = (int*)((char*)d_ws + 65536);                  // 2 MB
    float* stats = (float*)((char*)d_ws + 65536 + 2097152);     // 32 KB
    size_t zoff = 65536 + 2097152 + (size_t)NBUCK*512*4;
    float* zbuf = (float*)((char*)d_ws + zoff);                 // 128 MB (proven fits)
    float* mmbuf = zbuf + (size_t)B_*M_ * 2048;                 // +16 MB (guarded)
    size_t need_mm = zoff + (size_t)B_*M_ * 2048 * 4 + (size_t)B_*M_ * 256 * 4;
    bool have_mm = ws_size >= need_mm;

    hipMemsetAsync(stats, 0, NBUCK*512*sizeof(float), stream);
    fps_kernel<<<B_, FPS_T, 0, stream>>>(xyz, fps_i, out_xyz);
    ballq_kernel<<<B_ * (M_/BQ_G), 256, 0, stream>>>(xyz, fps_i, ball_i);
    mlpS1_kernel<<<(B_*M_)/MCEN, 256, 0, stream>>>(xyz, feat, fps_i, ball_i, w0, b0, zbuf, stats);
    mlpS2_kernel<<<(B_*M_)/MCEN, 256, 0, stream>>>(zbuf, w1, b1, g0, be0, stats);
    if (have_mm) {
        mlpS3_kernel<1><<<(B_*M_)/MCEN, 256, 0, stream>>>(zbuf, w2, b2, g1, be1, mmbuf, stats);
        mlpS4m_kernel<<<512, 256, 0, stream>>>(mmbuf, g2, be2, stats, out_feat);
    } else {
        mlpS3_kernel<0><<<(B_*M_)/MCEN, 256, 0, stream>>>(zbuf, w2, b2, g1, be1, mmbuf, stats);
        mlpS4r_kernel<<<(B_*M_)/MCEN, 256, 0, stream>>>(zbuf, w2, b2, g1, be1, g2, be2, stats, out_feat);
    }
}

// Round 12
// 1482.027 us; speedup vs baseline: 1.0037x; 1.0037x over previous
//
#include <hip/hip_runtime.h>

#define B_ 16
#define N_ 4096
#define M_ 1024
#define S_ 32
#define IN_ 64
#define C0IN 67
#define C0 64
#define C1 64
#define C2 128
#define NTOT (B_*M_*S_)
#define R2 0.04f
#define CAP 1024
#define NBUCK 16
#define BQ_G 32
#define MCEN 16

#define FPS_T 256
#define FPS_PTS 16

// 64-bit DPP max (packed key).
#define DPP_U64_MAX(k, ctrl) { \
    unsigned int _lo = (unsigned int)(k), _hi = (unsigned int)((k) >> 32); \
    unsigned int _olo = (unsigned int)__builtin_amdgcn_update_dpp((int)_lo, (int)_lo, ctrl, 0xF, 0xF, false); \
    unsigned int _ohi = (unsigned int)__builtin_amdgcn_update_dpp((int)_hi, (int)_hi, ctrl, 0xF, 0xF, false); \
    unsigned long long _o = ((unsigned long long)_ohi << 32) | _olo; \
    if (_o > (k)) (k) = _o; }

// ---------------- FPS ---------------- (frozen, proven 662-667 us)
__global__ __launch_bounds__(FPS_T, 1) void fps_kernel(const float* __restrict__ xyz,
                                                       int* __restrict__ fps_idx,
                                                       float* __restrict__ out_xyz) {
#pragma clang fp contract(off)
    __shared__ float4 pxyz[N_];
    __shared__ int    sel[M_];
    __shared__ __align__(16) unsigned long long slotk[2][4];
    int b = blockIdx.x, t = threadIdx.x;
    const float* xb = xyz + (size_t)b * N_ * 3;
    float lx[FPS_PTS], ly[FPS_PTS], lz[FPS_PTS], dl[FPS_PTS];
#pragma unroll
    for (int j = 0; j < FPS_PTS; j++) {
        int i = (j << 8) + t;
        float x = xb[3*i], y = xb[3*i+1], z = xb[3*i+2];
        lx[j] = x; ly[j] = y; lz[j] = z;
        dl[j] = __builtin_inff();
        pxyz[i] = make_float4(x, y, z, 0.f);
    }
    __syncthreads();
    int wid = t >> 6, lane = t & 63;
    int cur = 0;
    float4 cc = pxyz[0];
    for (int k = 0; k < M_; k++) {
        float cx = cc.x, cy = cc.y, cz = cc.z;
        if (t == 0) sel[k] = cur;
#pragma unroll
        for (int j = 0; j < FPS_PTS; j++)
            asm volatile("" : "+v"(lx[j]), "+v"(ly[j]), "+v"(lz[j]));
        float bv = -1.0f; int bi = 0x7fffffff;
#pragma unroll
        for (int j = 0; j < FPS_PTS; j++) {
            float dx = lx[j] - cx, dy = ly[j] - cy, dz = lz[j] - cz;
            float t0 = dx*dx, t1 = dy*dy, t2 = dz*dz;
            float d = (t0 + t1) + t2;
            float od = dl[j];
            float nd = d < od ? d : od;
            dl[j] = nd;
            if (nd > bv) { bv = nd; bi = (j << 8) + t; }
        }
        unsigned long long key = ((unsigned long long)__float_as_uint(bv) << 32)
                               | (unsigned int)(~bi);
        DPP_U64_MAX(key, 0x111);
        DPP_U64_MAX(key, 0x112);
        DPP_U64_MAX(key, 0x114);
        DPP_U64_MAX(key, 0x118);
        DPP_U64_MAX(key, 0x142);
        DPP_U64_MAX(key, 0x143);
        int p = k & 1;
        if (lane == 63) slotk[p][wid] = key;
        __syncthreads();
        ulonglong2 s01 = *(const ulonglong2*)&slotk[p][0];
        ulonglong2 s23 = *(const ulonglong2*)&slotk[p][2];
        unsigned long long kk = s01.x;
        if (s01.y > kk) kk = s01.y;
        if (s23.x > kk) kk = s23.x;
        if (s23.y > kk) kk = s23.y;
        cur = (int)(~(unsigned int)kk);
        cc = pxyz[cur];
    }
    __syncthreads();
    for (int i = t; i < M_; i += FPS_T) {
        int ix = sel[i];
        float4 q = pxyz[ix];
        fps_idx[b*M_ + i] = ix;
        out_xyz[(b*M_ + i)*3 + 0] = q.x;
        out_xyz[(b*M_ + i)*3 + 1] = q.y;
        out_xyz[(b*M_ + i)*3 + 2] = q.z;
    }
}

// ---------------- Ball query (grouped, frozen) ----------------
__global__ __launch_bounds__(256) void ballq_kernel(const float* __restrict__ xyz,
                                                    const int* __restrict__ fps_idx,
                                                    int* __restrict__ ball_idx) {
#pragma clang fp contract(off)
    __shared__ float4 pts[N_];
    __shared__ float cd[CAP];
    __shared__ int   ci[CAP];
    __shared__ int   cnt;
    __shared__ float rv[4];
    __shared__ int   ri[4];
    __shared__ int   slots[33];
    int blk = blockIdx.x;
    int b = blk >> 5;
    int g = blk & 31;
    int t = threadIdx.x;
    const float* xb = xyz + (size_t)b * N_ * 3;
    for (int i = t; i < N_; i += 256)
        pts[i] = make_float4(xb[i*3+0], xb[i*3+1], xb[i*3+2], 0.f);
    __syncthreads();
    for (int mm = 0; mm < BQ_G; mm++) {
        int m = (g << 5) + mm;
        if (t == 0) cnt = 0;
        __syncthreads();
        float4 c4 = pts[fps_idx[b*M_ + m]];
        float cx = c4.x, cy = c4.y, cz = c4.z;
        float bv = 3.4e38f; int bi = 0x7fffffff;
        for (int i = t; i < N_; i += 256) {
            float4 p = pts[i];
            float dx = p.x - cx, dy = p.y - cy, dz = p.z - cz;
            float t0 = dx*dx, t1 = dy*dy, t2 = dz*dz;
            float d = (t0 + t1) + t2;
            if (d < bv || (d == bv && i < bi)) { bv = d; bi = i; }
            if (d <= R2) {
                int pp = atomicAdd(&cnt, 1);
                if (pp < CAP) { cd[pp] = d; ci[pp] = i; }
            }
        }
        for (int off = 32; off >= 1; off >>= 1) {
            float ov = __shfl_xor(bv, off, 64);
            int   oi = __shfl_xor(bi, off, 64);
            if (ov < bv || (ov == bv && oi < bi)) { bv = ov; bi = oi; }
        }
        int w = t >> 6;
        if ((t & 63) == 0) { rv[w] = bv; ri[w] = bi; }
        __syncthreads();
        int n = cnt < CAP ? cnt : CAP;
        for (int j = t; j < n; j += 256) {
            float dj = cd[j]; int ij = ci[j];
            int rank = 0;
            for (int k = 0; k < n; k++) {
                float dk = cd[k]; int ik = ci[k];
                rank += (dk < dj) || (dk == dj && ik < ij);
            }
            if (rank < S_) slots[rank] = ij;
        }
        if (t == 0) {
            float v = rv[0]; int ix = ri[0];
            for (int j = 1; j < 4; j++)
                if (rv[j] < v || (rv[j] == v && ri[j] < ix)) { v = rv[j]; ix = ri[j]; }
            slots[32] = ix;
        }
        __syncthreads();
        if (t < S_) {
            int nearest = (n > 0) ? slots[0] : slots[32];
            int ix = (t < n) ? slots[t] : nearest;
            ball_idx[(size_t)(b*M_ + m)*S_ + t] = ix;
        }
    }
}

// ============ Staged pipeline, MCEN centers per block ============
// S3 reduces each center's z2 to per-channel (zmax,zmin) and stores them
// IN-PLACE at zbuf[blk*2048 + 0..255] (z1 is dead after S3's reads -> zero
// extra workspace, no ws guard needed). Monotonicity makes S4 bit-exact:
// max_s relu(a*z+c) == relu(a*zmax+c) for a>0, relu(a*zmin+c) for a<0
// (IEEE mult/add by a constant is monotone; equality attained at the
// extremal sample; a==0 gives identical bits).

// S1: gather + L0 -> z0, stats0 (unchanged from round 10)
__global__ __launch_bounds__(256) void mlpS1_kernel(
    const float* __restrict__ xyz, const float* __restrict__ feat,
    const int* __restrict__ fps_idx, const int* __restrict__ ball_idx,
    const float* __restrict__ w0, const float* __restrict__ b0,
    float* __restrict__ zbuf, float* __restrict__ stats) {
    __shared__ __align__(16) float xs[S_][72];
    __shared__ float rsum[64][9], rsq[64][9];
    __shared__ int idxs[S_];
    int blk0 = blockIdx.x * MCEN, t = threadIdx.x;
    int b = blk0 >> 10;
    const float* xb = xyz + (size_t)b * N_ * 3;
    int dp = t & 31, sg = t >> 5;
    int d0 = dp * 2;
    float wA[72], wB[72];
    {
        const float* wa = w0 + (size_t)d0 * C0IN;
        const float* wb = wa + C0IN;
        wA[0] = wa[0]; wA[1] = wa[1]; wA[2] = wa[2]; wA[3] = 0.f;
        wB[0] = wb[0]; wB[1] = wb[1]; wB[2] = wb[2]; wB[3] = 0.f;
#pragma unroll
        for (int c = 0; c < 64; c++) { wA[4 + c] = wa[3 + c]; wB[4 + c] = wb[3 + c]; }
#pragma unroll
        for (int c = 68; c < 72; c++) { wA[c] = 0.f; wB[c] = 0.f; }
    }
    float bi0 = b0[d0], bi1 = b0[d0+1];
    if (t < 32) { xs[t][3] = 0.f; }
    else if (t < 160) { int s = (t - 32) >> 2; xs[s][68 + ((t - 32) & 3)] = 0.f; }
    float ls0 = 0.f, lq0 = 0.f, ls1 = 0.f, lq1 = 0.f;
    for (int e = 0; e < MCEN; e++) {
        int blk = blk0 + e;
        int m = blk & (M_ - 1);
        int cidx = fps_idx[b*M_ + m];
        float cx = xb[cidx*3+0], cy = xb[cidx*3+1], cz = xb[cidx*3+2];
        if (t < S_) idxs[t] = ball_idx[(size_t)blk * S_ + t];
        __syncthreads();
#pragma unroll
        for (int ii = 0; ii < 2; ii++) {
            int i = t + ii * 256;
            int s = i >> 4, c4 = i & 15;
            int p = idxs[s];
            float4 v = *(const float4*)&feat[((size_t)b*N_ + p)*IN_ + 4*c4];
            *(float4*)&xs[s][4 + 4*c4] = v;
        }
        if (t < 96) {
            int s = t >> 2, comp = t & 3;
            if (comp < 3) {
                int p = idxs[s];
                float v = (comp == 0) ? xb[p*3+0] - cx
                        : (comp == 1) ? xb[p*3+1] - cy
                                      : xb[p*3+2] - cz;
                xs[s][comp] = v;
            }
        } else if (t < 224) {
            int tt = t - 96;
            int s = 24 + (tt >> 2), comp = tt & 3;
            if (comp < 3 && s < 32) {
                int p = idxs[s];
                float v = (comp == 0) ? xb[p*3+0] - cx
                        : (comp == 1) ? xb[p*3+1] - cy
                                      : xb[p*3+2] - cz;
                xs[s][comp] = v;
            }
        }
        __syncthreads();
        float acc0[4], acc1[4];
#pragma unroll
        for (int q = 0; q < 4; q++) { acc0[q] = bi0; acc1[q] = bi1; }
#pragma unroll
        for (int q = 0; q < 4; q++) {
            const float4* x4 = (const float4*)&xs[sg*4 + q][0];
#pragma unroll
            for (int c4 = 0; c4 < 18; c4++) {
                float4 v = x4[c4];
                acc0[q] += v.x * wA[4*c4+0]; acc1[q] += v.x * wB[4*c4+0];
                acc0[q] += v.y * wA[4*c4+1]; acc1[q] += v.y * wB[4*c4+1];
                acc0[q] += v.z * wA[4*c4+2]; acc1[q] += v.z * wB[4*c4+2];
                acc0[q] += v.w * wA[4*c4+3]; acc1[q] += v.w * wB[4*c4+3];
            }
        }
        float* zt = zbuf + (size_t)blk * 2048;
#pragma unroll
        for (int q = 0; q < 4; q++) {
            int s = sg*4 + q;
            *(float2*)&zt[s*64 + d0] = make_float2(acc0[q], acc1[q]);
            ls0 += acc0[q]; lq0 += acc0[q]*acc0[q];
            ls1 += acc1[q]; lq1 += acc1[q]*acc1[q];
        }
    }
    rsum[d0][sg] = ls0; rsq[d0][sg] = lq0;
    rsum[d0+1][sg] = ls1; rsq[d0+1][sg] = lq1;
    __syncthreads();
    if (t < 64) {
        float s = 0.f, s2 = 0.f;
#pragma unroll
        for (int j = 0; j < 8; j++) { s += rsum[t][j]; s2 += rsq[t][j]; }
        float* sb = stats + (size_t)(blockIdx.x & (NBUCK-1)) * 512;
        atomicAdd(&sb[t], s);
        atomicAdd(&sb[64 + t], s2);
    }
}

// S2: z0 -> BN0+relu -> L1 -> z1 (in-place), stats1. float4 z loads.
__global__ __launch_bounds__(256) void mlpS2_kernel(
    float* __restrict__ zbuf,
    const float* __restrict__ w1, const float* __restrict__ b1,
    const float* __restrict__ g0, const float* __restrict__ be0,
    float* __restrict__ stats) {
    __shared__ __align__(16) float y0s[S_][C0];
    __shared__ float rsum[64][9], rsq[64][9];
    __shared__ __align__(16) float lc[128];
    int blk0 = blockIdx.x * MCEN, t = threadIdx.x;
    const float inv_n = 1.0f / (float)NTOT;
    if (t < 64) {
        float s = 0.f, s2 = 0.f;
        for (int j = 0; j < NBUCK; j++) { s += stats[j*512 + t]; s2 += stats[j*512 + 64 + t]; }
        float mean = s * inv_n, var = s2 * inv_n - mean * mean;
        float a = g0[t] * (1.0f / sqrtf(var + 1e-5f));
        lc[t] = a; lc[64 + t] = be0[t] - mean * a;
    }
    int dv = (4*t) & 63;
    int dp = t & 31, sg = t >> 5;
    int d0 = dp * 2;
    float wA[64], wB[64];
    {
        const float4* wa4 = (const float4*)(w1 + (size_t)d0 * C0);
        const float4* wb4 = (const float4*)(w1 + (size_t)(d0+1) * C0);
#pragma unroll
        for (int c4 = 0; c4 < 16; c4++) {
            float4 a = wa4[c4], bb = wb4[c4];
            wA[4*c4+0] = a.x;  wA[4*c4+1] = a.y;  wA[4*c4+2] = a.z;  wA[4*c4+3] = a.w;
            wB[4*c4+0] = bb.x; wB[4*c4+1] = bb.y; wB[4*c4+2] = bb.z; wB[4*c4+3] = bb.w;
        }
    }
    float bi0 = b1[d0], bi1 = b1[d0+1];
    __syncthreads();   // lc ready
    float4 av = *(const float4*)&lc[dv];
    float4 cv = *(const float4*)&lc[64 + dv];
    float ls0 = 0.f, lq0 = 0.f, ls1 = 0.f, lq1 = 0.f;
    for (int e = 0; e < MCEN; e++) {
        int blk = blk0 + e;
        float* zt = zbuf + (size_t)blk * 2048;
        float4 zv0 = *(const float4*)&zt[4*t];
        float4 zv1 = *(const float4*)&zt[4*t + 1024];
        if (e) __syncthreads();              // y0s reuse guard
        {
            int s0 = (4*t) >> 6, s1 = s0 + 16;
            float4 y0, y1;
            y0.x = zv0.x*av.x + cv.x; y0.y = zv0.y*av.y + cv.y;
            y0.z = zv0.z*av.z + cv.z; y0.w = zv0.w*av.w + cv.w;
            y1.x = zv1.x*av.x + cv.x; y1.y = zv1.y*av.y + cv.y;
            y1.z = zv1.z*av.z + cv.z; y1.w = zv1.w*av.w + cv.w;
            y0.x = y0.x > 0.f ? y0.x : 0.f; y0.y = y0.y > 0.f ? y0.y : 0.f;
            y0.z = y0.z > 0.f ? y0.z : 0.f; y0.w = y0.w > 0.f ? y0.w : 0.f;
            y1.x = y1.x > 0.f ? y1.x : 0.f; y1.y = y1.y > 0.f ? y1.y : 0.f;
            y1.z = y1.z > 0.f ? y1.z : 0.f; y1.w = y1.w > 0.f ? y1.w : 0.f;
            *(float4*)&y0s[s0][dv] = y0;
            *(float4*)&y0s[s1][dv] = y1;
        }
        __syncthreads();                     // y0s ready
        float acc0[4], acc1[4];
#pragma unroll
        for (int q = 0; q < 4; q++) { acc0[q] = bi0; acc1[q] = bi1; }
#pragma unroll
        for (int q = 0; q < 4; q++) {
            const float4* x4 = (const float4*)&y0s[sg*4 + q][0];
#pragma unroll
            for (int c4 = 0; c4 < 16; c4++) {
                float4 v = x4[c4];
                acc0[q] += v.x * wA[4*c4+0]; acc1[q] += v.x * wB[4*c4+0];
                acc0[q] += v.y * wA[4*c4+1]; acc1[q] += v.y * wB[4*c4+1];
                acc0[q] += v.z * wA[4*c4+2]; acc1[q] += v.z * wB[4*c4+2];
                acc0[q] += v.w * wA[4*c4+3]; acc1[q] += v.w * wB[4*c4+3];
            }
        }
#pragma unroll
        for (int q = 0; q < 4; q++) {
            int s = sg*4 + q;
            *(float2*)&zt[s*64 + d0] = make_float2(acc0[q], acc1[q]);
            ls0 += acc0[q]; lq0 += acc0[q]*acc0[q];
            ls1 += acc1[q]; lq1 += acc1[q]*acc1[q];
        }
    }
    rsum[d0][sg] = ls0; rsq[d0][sg] = lq0;
    rsum[d0+1][sg] = ls1; rsq[d0+1][sg] = lq1;
    __syncthreads();
    if (t < 64) {
        float s = 0.f, s2 = 0.f;
#pragma unroll
        for (int j = 0; j < 8; j++) { s += rsum[t][j]; s2 += rsq[t][j]; }
        float* sb = stats + (size_t)(blockIdx.x & (NBUCK-1)) * 512;
        atomicAdd(&sb[128 + t], s);
        atomicAdd(&sb[192 + t], s2);
    }
}

// S3: z1 -> BN1+relu -> L2 -> stats2 + per-center (zmax,zmin) written
// IN-PLACE to zbuf[blk*2048 + 0..255] (z1 dead after this kernel's reads).
__global__ __launch_bounds__(256) void mlpS3_kernel(
    float* __restrict__ zbuf,
    const float* __restrict__ w2, const float* __restrict__ b2,
    const float* __restrict__ g1, const float* __restrict__ be1,
    float* __restrict__ stats) {
    __shared__ __align__(16) float y1s[S_][C1];
    __shared__ float rsum[128][5], rsq[128][5];
    __shared__ float rmx[128][5], rmn[128][5];
    __shared__ __align__(16) float lc[128];
    int blk0 = blockIdx.x * MCEN, t = threadIdx.x;
    const float inv_n = 1.0f / (float)NTOT;
    if (t < 64) {
        float s = 0.f, s2 = 0.f;
        for (int j = 0; j < NBUCK; j++) { s += stats[j*512 + 128 + t]; s2 += stats[j*512 + 192 + t]; }
        float mean = s * inv_n, var = s2 * inv_n - mean * mean;
        float a = g1[t] * (1.0f / sqrtf(var + 1e-5f));
        lc[t] = a; lc[64 + t] = be1[t] - mean * a;
    }
    int dv = (4*t) & 63;
    int dp = t & 63, sg = t >> 6;
    int d0 = dp * 2;
    float wA[64], wB[64];
    {
        const float4* wa4 = (const float4*)(w2 + (size_t)d0 * C1);
        const float4* wb4 = (const float4*)(w2 + (size_t)(d0+1) * C1);
#pragma unroll
        for (int c4 = 0; c4 < 16; c4++) {
            float4 a = wa4[c4], bb = wb4[c4];
            wA[4*c4+0] = a.x;  wA[4*c4+1] = a.y;  wA[4*c4+2] = a.z;  wA[4*c4+3] = a.w;
            wB[4*c4+0] = bb.x; wB[4*c4+1] = bb.y; wB[4*c4+2] = bb.z; wB[4*c4+3] = bb.w;
        }
    }
    float bi0 = b2[d0], bi1 = b2[d0+1];
    __syncthreads();   // lc ready
    float4 av = *(const float4*)&lc[dv];
    float4 cv = *(const float4*)&lc[64 + dv];
    float ls0 = 0.f, lq0 = 0.f, ls1 = 0.f, lq1 = 0.f;
    for (int e = 0; e < MCEN; e++) {
        int blk = blk0 + e;
        float* zt = zbuf + (size_t)blk * 2048;
        float4 zv0 = *(const float4*)&zt[4*t];
        float4 zv1 = *(const float4*)&zt[4*t + 1024];
        if (e) __syncthreads();              // y1s/rmx/rmn reuse guard
        {
            int s0 = (4*t) >> 6, s1 = s0 + 16;
            float4 y0, y1;
            y0.x = zv0.x*av.x + cv.x; y0.y = zv0.y*av.y + cv.y;
            y0.z = zv0.z*av.z + cv.z; y0.w = zv0.w*av.w + cv.w;
            y1.x = zv1.x*av.x + cv.x; y1.y = zv1.y*av.y + cv.y;
            y1.z = zv1.z*av.z + cv.z; y1.w = zv1.w*av.w + cv.w;
            y0.x = y0.x > 0.f ? y0.x : 0.f; y0.y = y0.y > 0.f ? y0.y : 0.f;
            y0.z = y0.z > 0.f ? y0.z : 0.f; y0.w = y0.w > 0.f ? y0.w : 0.f;
            y1.x = y1.x > 0.f ? y1.x : 0.f; y1.y = y1.y > 0.f ? y1.y : 0.f;
            y1.z = y1.z > 0.f ? y1.z : 0.f; y1.w = y1.w > 0.f ? y1.w : 0.f;
            *(float4*)&y1s[s0][dv] = y0;
            *(float4*)&y1s[s1][dv] = y1;
        }
        __syncthreads();                     // y1s ready (all zt reads consumed)
        float acc0[8], acc1[8];
#pragma unroll
        for (int q = 0; q < 8; q++) { acc0[q] = bi0; acc1[q] = bi1; }
#pragma unroll
        for (int q = 0; q < 8; q++) {
            const float4* x4 = (const float4*)&y1s[sg*8 + q][0];
#pragma unroll
            for (int c4 = 0; c4 < 16; c4++) {
                float4 v = x4[c4];
                acc0[q] += v.x * wA[4*c4+0]; acc1[q] += v.x * wB[4*c4+0];
                acc0[q] += v.y * wA[4*c4+1]; acc1[q] += v.y * wB[4*c4+1];
                acc0[q] += v.z * wA[4*c4+2]; acc1[q] += v.z * wB[4*c4+2];
                acc0[q] += v.w * wA[4*c4+3]; acc1[q] += v.w * wB[4*c4+3];
            }
        }
#pragma unroll
        for (int q = 0; q < 8; q++) {
            ls0 += acc0[q]; lq0 += acc0[q]*acc0[q];
            ls1 += acc1[q]; lq1 += acc1[q]*acc1[q];
        }
        // per-center (zmax,zmin) -> in-place zbuf[blk*2048 + 0..255]
        {
            float m0 = acc0[0], n0 = acc0[0], m1 = acc1[0], n1 = acc1[0];
#pragma unroll
            for (int q = 1; q < 8; q++) {
                m0 = acc0[q] > m0 ? acc0[q] : m0;  n0 = acc0[q] < n0 ? acc0[q] : n0;
                m1 = acc1[q] > m1 ? acc1[q] : m1;  n1 = acc1[q] < n1 ? acc1[q] : n1;
            }
            rmx[d0][sg] = m0; rmn[d0][sg] = n0;
            rmx[d0+1][sg] = m1; rmn[d0+1][sg] = n1;
            __syncthreads();                 // minmax ready
            if (t < 128) {
                float mx = rmx[t][0], mn = rmn[t][0];
#pragma unroll
                for (int j = 1; j < 4; j++) {
                    mx = rmx[t][j] > mx ? rmx[t][j] : mx;
                    mn = rmn[t][j] < mn ? rmn[t][j] : mn;
                }
                zt[t] = mx;
                zt[128 + t] = mn;
            }
        }
    }
    rsum[d0][sg] = ls0; rsq[d0][sg] = lq0;
    rsum[d0+1][sg] = ls1; rsq[d0+1][sg] = lq1;
    __syncthreads();
    if (t < 128) {
        float s = 0.f, s2 = 0.f;
#pragma unroll
        for (int j = 0; j < 4; j++) { s += rsum[t][j]; s2 += rsq[t][j]; }
        float* sb = stats + (size_t)(blockIdx.x & (NBUCK-1)) * 512;
        atomicAdd(&sb[256 + t], s);
        atomicAdd(&sb[384 + t], s2);
    }
}

// S4m: out[cen][d] = relu(a * (a>0 ? zmax : zmin) + c) — bit-exact vs
// max over samples. Reads mm from zbuf in-place (stride 2048 floats).
__global__ __launch_bounds__(256) void mlpS4m_kernel(
    const float* __restrict__ zbuf,
    const float* __restrict__ g2, const float* __restrict__ be2,
    const float* __restrict__ stats, float* __restrict__ out_feat) {
    __shared__ float lc[256];
    int blk = blockIdx.x, t = threadIdx.x;
    const float inv_n = 1.0f / (float)NTOT;
    if (t < 128) {
        float s = 0.f, s2 = 0.f;
        for (int j = 0; j < NBUCK; j++) { s += stats[j*512 + 256 + t]; s2 += stats[j*512 + 384 + t]; }
        float mean = s * inv_n, var = s2 * inv_n - mean * mean;
        float a = g2[t] * (1.0f / sqrtf(var + 1e-5f));
        lc[t] = a; lc[128 + t] = be2[t] - mean * a;
    }
    __syncthreads();
    size_t base = (size_t)blk * 4096;   // 512 blocks x 4096 outputs
    for (int i = t; i < 4096; i += 256) {
        size_t gi = base + i;
        int cen = (int)(gi >> 7), d = (int)(gi & 127);
        float a = lc[d], c = lc[128 + d];
        float z = (a > 0.f) ? zbuf[(size_t)cen*2048 + d] : zbuf[(size_t)cen*2048 + 128 + d];
        float v = a * z + c;
        out_feat[gi] = v > 0.f ? v : 0.f;
    }
}

extern "C" void kernel_launch(void* const* d_in, const int* in_sizes, int n_in,
                              void* d_out, int out_size, void* d_ws, size_t ws_size,
                              hipStream_t stream) {
    const float* xyz  = (const float*)d_in[0];
    const float* feat = (const float*)d_in[1];
    const float* w0 = (const float*)d_in[2];  const float* b0 = (const float*)d_in[3];
    const float* g0 = (const float*)d_in[4];  const float* be0 = (const float*)d_in[5];
    const float* w1 = (const float*)d_in[6];  const float* b1 = (const float*)d_in[7];
    const float* g1 = (const float*)d_in[8];  const float* be1 = (const float*)d_in[9];
    const float* w2 = (const float*)d_in[10]; const float* b2 = (const float*)d_in[11];
    const float* g2 = (const float*)d_in[12]; const float* be2 = (const float*)d_in[13];
    float* out_xyz  = (float*)d_out;
    float* out_feat = out_xyz + B_*M_*3;

    int* fps_i  = (int*)d_ws;                                   // 64 KB
    int* ball_i = (int*)((char*)d_ws + 65536);                  // 2 MB
    float* stats = (float*)((char*)d_ws + 65536 + 2097152);     // 32 KB
    size_t zoff = 65536 + 2097152 + (size_t)NBUCK*512*4;
    float* zbuf = (float*)((char*)d_ws + zoff);                 // 128 MB (proven fits, round 6)

    hipMemsetAsync(stats, 0, NBUCK*512*sizeof(float), stream);
    fps_kernel<<<B_, FPS_T, 0, stream>>>(xyz, fps_i, out_xyz);
    ballq_kernel<<<B_ * (M_/BQ_G), 256, 0, stream>>>(xyz, fps_i, ball_i);
    mlpS1_kernel<<<(B_*M_)/MCEN, 256, 0, stream>>>(xyz, feat, fps_i, ball_i, w0, b0, zbuf, stats);
    mlpS2_kernel<<<(B_*M_)/MCEN, 256, 0, stream>>>(zbuf, w1, b1, g0, be0, stats);
    mlpS3_kernel<<<(B_*M_)/MCEN, 256, 0, stream>>>(zbuf, w2, b2, g1, be1, stats);
    mlpS4m_kernel<<<512, 256, 0, stream>>>(zbuf, g2, be2, stats, out_feat);
}

// Round 13
// 1468.198 us; speedup vs baseline: 1.0132x; 1.0094x over previous
//
#include <hip/hip_runtime.h>

#define B_ 16
#define N_ 4096
#define M_ 1024
#define S_ 32
#define IN_ 64
#define C0IN 67
#define C0 64
#define C1 64
#define C2 128
#define NTOT (B_*M_*S_)
#define R2 0.04f
#define CAP 1024
#define NBUCK 16
#define BQ_G 32
#define MCEN 16

#define FPS_T 256
#define FPS_PTS 16

// 64-bit DPP max (packed key).
#define DPP_U64_MAX(k, ctrl) { \
    unsigned int _lo = (unsigned int)(k), _hi = (unsigned int)((k) >> 32); \
    unsigned int _olo = (unsigned int)__builtin_amdgcn_update_dpp((int)_lo, (int)_lo, ctrl, 0xF, 0xF, false); \
    unsigned int _ohi = (unsigned int)__builtin_amdgcn_update_dpp((int)_hi, (int)_hi, ctrl, 0xF, 0xF, false); \
    unsigned long long _o = ((unsigned long long)_ohi << 32) | _olo; \
    if (_o > (k)) (k) = _o; }

// ---------------- FPS ---------------- (frozen, proven 661-667 us)
__global__ __launch_bounds__(FPS_T, 1) void fps_kernel(const float* __restrict__ xyz,
                                                       int* __restrict__ fps_idx,
                                                       float* __restrict__ out_xyz) {
#pragma clang fp contract(off)
    __shared__ float4 pxyz[N_];
    __shared__ int    sel[M_];
    __shared__ __align__(16) unsigned long long slotk[2][4];
    int b = blockIdx.x, t = threadIdx.x;
    const float* xb = xyz + (size_t)b * N_ * 3;
    float lx[FPS_PTS], ly[FPS_PTS], lz[FPS_PTS], dl[FPS_PTS];
#pragma unroll
    for (int j = 0; j < FPS_PTS; j++) {
        int i = (j << 8) + t;
        float x = xb[3*i], y = xb[3*i+1], z = xb[3*i+2];
        lx[j] = x; ly[j] = y; lz[j] = z;
        dl[j] = __builtin_inff();
        pxyz[i] = make_float4(x, y, z, 0.f);
    }
    __syncthreads();
    int wid = t >> 6, lane = t & 63;
    int cur = 0;
    float4 cc = pxyz[0];
    for (int k = 0; k < M_; k++) {
        float cx = cc.x, cy = cc.y, cz = cc.z;
        if (t == 0) sel[k] = cur;
#pragma unroll
        for (int j = 0; j < FPS_PTS; j++)
            asm volatile("" : "+v"(lx[j]), "+v"(ly[j]), "+v"(lz[j]));
        float bv = -1.0f; int bi = 0x7fffffff;
#pragma unroll
        for (int j = 0; j < FPS_PTS; j++) {
            float dx = lx[j] - cx, dy = ly[j] - cy, dz = lz[j] - cz;
            float t0 = dx*dx, t1 = dy*dy, t2 = dz*dz;
            float d = (t0 + t1) + t2;
            float od = dl[j];
            float nd = d < od ? d : od;
            dl[j] = nd;
            if (nd > bv) { bv = nd; bi = (j << 8) + t; }
        }
        unsigned long long key = ((unsigned long long)__float_as_uint(bv) << 32)
                               | (unsigned int)(~bi);
        DPP_U64_MAX(key, 0x111);
        DPP_U64_MAX(key, 0x112);
        DPP_U64_MAX(key, 0x114);
        DPP_U64_MAX(key, 0x118);
        DPP_U64_MAX(key, 0x142);
        DPP_U64_MAX(key, 0x143);
        int p = k & 1;
        if (lane == 63) slotk[p][wid] = key;
        __syncthreads();
        ulonglong2 s01 = *(const ulonglong2*)&slotk[p][0];
        ulonglong2 s23 = *(const ulonglong2*)&slotk[p][2];
        unsigned long long kk = s01.x;
        if (s01.y > kk) kk = s01.y;
        if (s23.x > kk) kk = s23.x;
        if (s23.y > kk) kk = s23.y;
        cur = (int)(~(unsigned int)kk);
        cc = pxyz[cur];
    }
    __syncthreads();
    for (int i = t; i < M_; i += FPS_T) {
        int ix = sel[i];
        float4 q = pxyz[ix];
        fps_idx[b*M_ + i] = ix;
        out_xyz[(b*M_ + i)*3 + 0] = q.x;
        out_xyz[(b*M_ + i)*3 + 1] = q.y;
        out_xyz[(b*M_ + i)*3 + 2] = q.z;
    }
}

// ---------------- Ball query (grouped, frozen) ----------------
__global__ __launch_bounds__(256) void ballq_kernel(const float* __restrict__ xyz,
                                                    const int* __restrict__ fps_idx,
                                                    int* __restrict__ ball_idx) {
#pragma clang fp contract(off)
    __shared__ float4 pts[N_];
    __shared__ float cd[CAP];
    __shared__ int   ci[CAP];
    __shared__ int   cnt;
    __shared__ float rv[4];
    __shared__ int   ri[4];
    __shared__ int   slots[33];
    int blk = blockIdx.x;
    int b = blk >> 5;
    int g = blk & 31;
    int t = threadIdx.x;
    const float* xb = xyz + (size_t)b * N_ * 3;
    for (int i = t; i < N_; i += 256)
        pts[i] = make_float4(xb[i*3+0], xb[i*3+1], xb[i*3+2], 0.f);
    __syncthreads();
    for (int mm = 0; mm < BQ_G; mm++) {
        int m = (g << 5) + mm;
        if (t == 0) cnt = 0;
        __syncthreads();
        float4 c4 = pts[fps_idx[b*M_ + m]];
        float cx = c4.x, cy = c4.y, cz = c4.z;
        float bv = 3.4e38f; int bi = 0x7fffffff;
        for (int i = t; i < N_; i += 256) {
            float4 p = pts[i];
            float dx = p.x - cx, dy = p.y - cy, dz = p.z - cz;
            float t0 = dx*dx, t1 = dy*dy, t2 = dz*dz;
            float d = (t0 + t1) + t2;
            if (d < bv || (d == bv && i < bi)) { bv = d; bi = i; }
            if (d <= R2) {
                int pp = atomicAdd(&cnt, 1);
                if (pp < CAP) { cd[pp] = d; ci[pp] = i; }
            }
        }
        for (int off = 32; off >= 1; off >>= 1) {
            float ov = __shfl_xor(bv, off, 64);
            int   oi = __shfl_xor(bi, off, 64);
            if (ov < bv || (ov == bv && oi < bi)) { bv = ov; bi = oi; }
        }
        int w = t >> 6;
        if ((t & 63) == 0) { rv[w] = bv; ri[w] = bi; }
        __syncthreads();
        int n = cnt < CAP ? cnt : CAP;
        for (int j = t; j < n; j += 256) {
            float dj = cd[j]; int ij = ci[j];
            int rank = 0;
            for (int k = 0; k < n; k++) {
                float dk = cd[k]; int ik = ci[k];
                rank += (dk < dj) || (dk == dj && ik < ij);
            }
            if (rank < S_) slots[rank] = ij;
        }
        if (t == 0) {
            float v = rv[0]; int ix = ri[0];
            for (int j = 1; j < 4; j++)
                if (rv[j] < v || (rv[j] == v && ri[j] < ix)) { v = rv[j]; ix = ri[j]; }
            slots[32] = ix;
        }
        __syncthreads();
        if (t < S_) {
            int nearest = (n > 0) ? slots[0] : slots[32];
            int ix = (t < n) ? slots[t] : nearest;
            ball_idx[(size_t)(b*M_ + m)*S_ + t] = ix;
        }
    }
}

// ============ Staged pipeline, MCEN centers per block ============
// ROUND 13: software-pipeline the per-center global loads one center ahead
// (T14 async-stage split). Arithmetic and accumulation order untouched ->
// bit-identical outputs; only load scheduling changes.

// S1: gather + L0 -> z0, stats0. Double-buffered xs; next center's feat/xyz
// prefetched to regs during current center's compute.
__global__ __launch_bounds__(256) void mlpS1_kernel(
    const float* __restrict__ xyz, const float* __restrict__ feat,
    const int* __restrict__ fps_idx, const int* __restrict__ ball_idx,
    const float* __restrict__ w0, const float* __restrict__ b0,
    float* __restrict__ zbuf, float* __restrict__ stats) {
    __shared__ __align__(16) float xs[2][S_][72];
    __shared__ float rsum[64][9], rsq[64][9];
    int blk0 = blockIdx.x * MCEN, t = threadIdx.x;
    int b = blk0 >> 10;
    const float* xb = xyz + (size_t)b * N_ * 3;
    int dp = t & 31, sg = t >> 5;
    int d0 = dp * 2;
    float wA[72], wB[72];
    {
        const float* wa = w0 + (size_t)d0 * C0IN;
        const float* wb = wa + C0IN;
        wA[0] = wa[0]; wA[1] = wa[1]; wA[2] = wa[2]; wA[3] = 0.f;
        wB[0] = wb[0]; wB[1] = wb[1]; wB[2] = wb[2]; wB[3] = 0.f;
#pragma unroll
        for (int c = 0; c < 64; c++) { wA[4 + c] = wa[3 + c]; wB[4 + c] = wb[3 + c]; }
#pragma unroll
        for (int c = 68; c < 72; c++) { wA[c] = 0.f; wB[c] = 0.f; }
    }
    float bi0 = b0[d0], bi1 = b0[d0+1];
    // constant pads for BOTH buffers (never overwritten)
    if (t < 64) { xs[t >> 5][t & 31][3] = 0.f; }
    else if (t < 128) {
        int tt = t - 64;                 // 0..63 -> buf, s pairs
        int bf = tt >> 5, s = tt & 31;
        xs[bf][s][68] = 0.f; xs[bf][s][69] = 0.f; xs[bf][s][70] = 0.f; xs[bf][s][71] = 0.f;
    }
    // prefetch mapping: feat: s0 = t>>4 (c4 = t&15), s1 = s0+16; xyz: t<128 -> s=t>>2, comp=t&3 (comp<3)
    int fs0 = t >> 4, fc4 = t & 15;
    int xsamp = t >> 2, xcomp = t & 3;
    bool xact = (t < 128) && (xcomp < 3);
    // ---- prefetch center 0
    float4 pf0, pf1; float pxv = 0.f;
    {
        int blk = blk0;
        int m = blk & (M_ - 1);
        int cidx = fps_idx[b*M_ + m];
        int p0 = ball_idx[(size_t)blk * S_ + fs0];
        int p1 = ball_idx[(size_t)blk * S_ + fs0 + 16];
        pf0 = *(const float4*)&feat[((size_t)b*N_ + p0)*IN_ + 4*fc4];
        pf1 = *(const float4*)&feat[((size_t)b*N_ + p1)*IN_ + 4*fc4];
        if (xact) {
            int pp = ball_idx[(size_t)blk * S_ + xsamp];
            pxv = xb[pp*3 + xcomp] - xb[cidx*3 + xcomp];
        }
    }
    float ls0 = 0.f, lq0 = 0.f, ls1 = 0.f, lq1 = 0.f;
    for (int e = 0; e < MCEN; e++) {
        int p = e & 1;
        // stage current prefetch into xs[p]
        *(float4*)&xs[p][fs0][4 + 4*fc4] = pf0;
        *(float4*)&xs[p][fs0 + 16][4 + 4*fc4] = pf1;
        if (xact) xs[p][xsamp][xcomp] = pxv;
        // issue prefetch for e+1 (hidden under barrier + compute)
        if (e + 1 < MCEN) {
            int blk = blk0 + e + 1;
            int m = blk & (M_ - 1);
            int cidx = fps_idx[b*M_ + m];
            int p0 = ball_idx[(size_t)blk * S_ + fs0];
            int p1 = ball_idx[(size_t)blk * S_ + fs0 + 16];
            pf0 = *(const float4*)&feat[((size_t)b*N_ + p0)*IN_ + 4*fc4];
            pf1 = *(const float4*)&feat[((size_t)b*N_ + p1)*IN_ + 4*fc4];
            if (xact) {
                int pp = ball_idx[(size_t)blk * S_ + xsamp];
                pxv = xb[pp*3 + xcomp] - xb[cidx*3 + xcomp];
            }
        }
        __syncthreads();                 // xs[p] ready; prior reads of xs[p^1] drained
        float acc0[4], acc1[4];
#pragma unroll
        for (int q = 0; q < 4; q++) { acc0[q] = bi0; acc1[q] = bi1; }
#pragma unroll
        for (int q = 0; q < 4; q++) {
            const float4* x4 = (const float4*)&xs[p][sg*4 + q][0];
#pragma unroll
            for (int c4 = 0; c4 < 18; c4++) {
                float4 v = x4[c4];
                acc0[q] += v.x * wA[4*c4+0]; acc1[q] += v.x * wB[4*c4+0];
                acc0[q] += v.y * wA[4*c4+1]; acc1[q] += v.y * wB[4*c4+1];
                acc0[q] += v.z * wA[4*c4+2]; acc1[q] += v.z * wB[4*c4+2];
                acc0[q] += v.w * wA[4*c4+3]; acc1[q] += v.w * wB[4*c4+3];
            }
        }
        float* zt = zbuf + (size_t)(blk0 + e) * 2048;
#pragma unroll
        for (int q = 0; q < 4; q++) {
            int s = sg*4 + q;
            *(float2*)&zt[s*64 + d0] = make_float2(acc0[q], acc1[q]);
            ls0 += acc0[q]; lq0 += acc0[q]*acc0[q];
            ls1 += acc1[q]; lq1 += acc1[q]*acc1[q];
        }
    }
    rsum[d0][sg] = ls0; rsq[d0][sg] = lq0;
    rsum[d0+1][sg] = ls1; rsq[d0+1][sg] = lq1;
    __syncthreads();
    if (t < 64) {
        float s = 0.f, s2 = 0.f;
#pragma unroll
        for (int j = 0; j < 8; j++) { s += rsum[t][j]; s2 += rsq[t][j]; }
        float* sb = stats + (size_t)(blockIdx.x & (NBUCK-1)) * 512;
        atomicAdd(&sb[t], s);
        atomicAdd(&sb[64 + t], s2);
    }
}

// S2: z0 -> BN0+relu -> L1 -> z1 (in-place), stats1. z loads prefetched 1 ahead.
__global__ __launch_bounds__(256) void mlpS2_kernel(
    float* __restrict__ zbuf,
    const float* __restrict__ w1, const float* __restrict__ b1,
    const float* __restrict__ g0, const float* __restrict__ be0,
    float* __restrict__ stats) {
    __shared__ __align__(16) float y0s[S_][C0];
    __shared__ float rsum[64][9], rsq[64][9];
    __shared__ __align__(16) float lc[128];
    int blk0 = blockIdx.x * MCEN, t = threadIdx.x;
    const float inv_n = 1.0f / (float)NTOT;
    if (t < 64) {
        float s = 0.f, s2 = 0.f;
        for (int j = 0; j < NBUCK; j++) { s += stats[j*512 + t]; s2 += stats[j*512 + 64 + t]; }
        float mean = s * inv_n, var = s2 * inv_n - mean * mean;
        float a = g0[t] * (1.0f / sqrtf(var + 1e-5f));
        lc[t] = a; lc[64 + t] = be0[t] - mean * a;
    }
    int dv = (4*t) & 63;
    int dp = t & 31, sg = t >> 5;
    int d0 = dp * 2;
    float wA[64], wB[64];
    {
        const float4* wa4 = (const float4*)(w1 + (size_t)d0 * C0);
        const float4* wb4 = (const float4*)(w1 + (size_t)(d0+1) * C0);
#pragma unroll
        for (int c4 = 0; c4 < 16; c4++) {
            float4 a = wa4[c4], bb = wb4[c4];
            wA[4*c4+0] = a.x;  wA[4*c4+1] = a.y;  wA[4*c4+2] = a.z;  wA[4*c4+3] = a.w;
            wB[4*c4+0] = bb.x; wB[4*c4+1] = bb.y; wB[4*c4+2] = bb.z; wB[4*c4+3] = bb.w;
        }
    }
    float bi0 = b1[d0], bi1 = b1[d0+1];
    // prefetch center 0
    float4 zc0 = *(const float4*)&zbuf[(size_t)blk0 * 2048 + 4*t];
    float4 zc1 = *(const float4*)&zbuf[(size_t)blk0 * 2048 + 4*t + 1024];
    __syncthreads();   // lc ready
    float4 av = *(const float4*)&lc[dv];
    float4 cv = *(const float4*)&lc[64 + dv];
    float ls0 = 0.f, lq0 = 0.f, ls1 = 0.f, lq1 = 0.f;
    for (int e = 0; e < MCEN; e++) {
        float4 zn0, zn1;
        if (e + 1 < MCEN) {
            zn0 = *(const float4*)&zbuf[(size_t)(blk0 + e + 1) * 2048 + 4*t];
            zn1 = *(const float4*)&zbuf[(size_t)(blk0 + e + 1) * 2048 + 4*t + 1024];
        }
        if (e) __syncthreads();              // y0s reuse guard
        {
            int s0 = (4*t) >> 6, s1 = s0 + 16;
            float4 y0, y1;
            y0.x = zc0.x*av.x + cv.x; y0.y = zc0.y*av.y + cv.y;
            y0.z = zc0.z*av.z + cv.z; y0.w = zc0.w*av.w + cv.w;
            y1.x = zc1.x*av.x + cv.x; y1.y = zc1.y*av.y + cv.y;
            y1.z = zc1.z*av.z + cv.z; y1.w = zc1.w*av.w + cv.w;
            y0.x = y0.x > 0.f ? y0.x : 0.f; y0.y = y0.y > 0.f ? y0.y : 0.f;
            y0.z = y0.z > 0.f ? y0.z : 0.f; y0.w = y0.w > 0.f ? y0.w : 0.f;
            y1.x = y1.x > 0.f ? y1.x : 0.f; y1.y = y1.y > 0.f ? y1.y : 0.f;
            y1.z = y1.z > 0.f ? y1.z : 0.f; y1.w = y1.w > 0.f ? y1.w : 0.f;
            *(float4*)&y0s[s0][dv] = y0;
            *(float4*)&y0s[s1][dv] = y1;
        }
        __syncthreads();                     // y0s ready
        float acc0[4], acc1[4];
#pragma unroll
        for (int q = 0; q < 4; q++) { acc0[q] = bi0; acc1[q] = bi1; }
#pragma unroll
        for (int q = 0; q < 4; q++) {
            const float4* x4 = (const float4*)&y0s[sg*4 + q][0];
#pragma unroll
            for (int c4 = 0; c4 < 16; c4++) {
                float4 v = x4[c4];
                acc0[q] += v.x * wA[4*c4+0]; acc1[q] += v.x * wB[4*c4+0];
                acc0[q] += v.y * wA[4*c4+1]; acc1[q] += v.y * wB[4*c4+1];
                acc0[q] += v.z * wA[4*c4+2]; acc1[q] += v.z * wB[4*c4+2];
                acc0[q] += v.w * wA[4*c4+3]; acc1[q] += v.w * wB[4*c4+3];
            }
        }
        float* zt = zbuf + (size_t)(blk0 + e) * 2048;
#pragma unroll
        for (int q = 0; q < 4; q++) {
            int s = sg*4 + q;
            *(float2*)&zt[s*64 + d0] = make_float2(acc0[q], acc1[q]);
            ls0 += acc0[q]; lq0 += acc0[q]*acc0[q];
            ls1 += acc1[q]; lq1 += acc1[q]*acc1[q];
        }
        zc0 = zn0; zc1 = zn1;
    }
    rsum[d0][sg] = ls0; rsq[d0][sg] = lq0;
    rsum[d0+1][sg] = ls1; rsq[d0+1][sg] = lq1;
    __syncthreads();
    if (t < 64) {
        float s = 0.f, s2 = 0.f;
#pragma unroll
        for (int j = 0; j < 8; j++) { s += rsum[t][j]; s2 += rsq[t][j]; }
        float* sb = stats + (size_t)(blockIdx.x & (NBUCK-1)) * 512;
        atomicAdd(&sb[128 + t], s);
        atomicAdd(&sb[192 + t], s2);
    }
}

// S3: z1 -> BN1+relu -> L2 -> stats2 + per-center (zmax,zmin) in-place to
// zbuf[blk*2048 + 0..255]. z loads prefetched 1 ahead (different centers ->
// no overlap with the minmax writes).
__global__ __launch_bounds__(256) void mlpS3_kernel(
    float* __restrict__ zbuf,
    const float* __restrict__ w2, const float* __restrict__ b2,
    const float* __restrict__ g1, const float* __restrict__ be1,
    float* __restrict__ stats) {
    __shared__ __align__(16) float y1s[S_][C1];
    __shared__ float rsum[128][5], rsq[128][5];
    __shared__ float rmx[128][5], rmn[128][5];
    __shared__ __align__(16) float lc[128];
    int blk0 = blockIdx.x * MCEN, t = threadIdx.x;
    const float inv_n = 1.0f / (float)NTOT;
    if (t < 64) {
        float s = 0.f, s2 = 0.f;
        for (int j = 0; j < NBUCK; j++) { s += stats[j*512 + 128 + t]; s2 += stats[j*512 + 192 + t]; }
        float mean = s * inv_n, var = s2 * inv_n - mean * mean;
        float a = g1[t] * (1.0f / sqrtf(var + 1e-5f));
        lc[t] = a; lc[64 + t] = be1[t] - mean * a;
    }
    int dv = (4*t) & 63;
    int dp = t & 63, sg = t >> 6;
    int d0 = dp * 2;
    float wA[64], wB[64];
    {
        const float4* wa4 = (const float4*)(w2 + (size_t)d0 * C1);
        const float4* wb4 = (const float4*)(w2 + (size_t)(d0+1) * C1);
#pragma unroll
        for (int c4 = 0; c4 < 16; c4++) {
            float4 a = wa4[c4], bb = wb4[c4];
            wA[4*c4+0] = a.x;  wA[4*c4+1] = a.y;  wA[4*c4+2] = a.z;  wA[4*c4+3] = a.w;
            wB[4*c4+0] = bb.x; wB[4*c4+1] = bb.y; wB[4*c4+2] = bb.z; wB[4*c4+3] = bb.w;
        }
    }
    float bi0 = b2[d0], bi1 = b2[d0+1];
    // prefetch center 0
    float4 zc0 = *(const float4*)&zbuf[(size_t)blk0 * 2048 + 4*t];
    float4 zc1 = *(const float4*)&zbuf[(size_t)blk0 * 2048 + 4*t + 1024];
    __syncthreads();   // lc ready
    float4 av = *(const float4*)&lc[dv];
    float4 cv = *(const float4*)&lc[64 + dv];
    float ls0 = 0.f, lq0 = 0.f, ls1 = 0.f, lq1 = 0.f;
    for (int e = 0; e < MCEN; e++) {
        float4 zn0, zn1;
        if (e + 1 < MCEN) {
            zn0 = *(const float4*)&zbuf[(size_t)(blk0 + e + 1) * 2048 + 4*t];
            zn1 = *(const float4*)&zbuf[(size_t)(blk0 + e + 1) * 2048 + 4*t + 1024];
        }
        if (e) __syncthreads();              // y1s/rmx/rmn reuse guard
        {
            int s0 = (4*t) >> 6, s1 = s0 + 16;
            float4 y0, y1;
            y0.x = zc0.x*av.x + cv.x; y0.y = zc0.y*av.y + cv.y;
            y0.z = zc0.z*av.z + cv.z; y0.w = zc0.w*av.w + cv.w;
            y1.x = zc1.x*av.x + cv.x; y1.y = zc1.y*av.y + cv.y;
            y1.z = zc1.z*av.z + cv.z; y1.w = zc1.w*av.w + cv.w;
            y0.x = y0.x > 0.f ? y0.x : 0.f; y0.y = y0.y > 0.f ? y0.y : 0.f;
            y0.z = y0.z > 0.f ? y0.z : 0.f; y0.w = y0.w > 0.f ? y0.w : 0.f;
            y1.x = y1.x > 0.f ? y1.x : 0.f; y1.y = y1.y > 0.f ? y1.y : 0.f;
            y1.z = y1.z > 0.f ? y1.z : 0.f; y1.w = y1.w > 0.f ? y1.w : 0.f;
            *(float4*)&y1s[s0][dv] = y0;
            *(float4*)&y1s[s1][dv] = y1;
        }
        __syncthreads();                     // y1s ready (all z reads of center e consumed)
        float acc0[8], acc1[8];
#pragma unroll
        for (int q = 0; q < 8; q++) { acc0[q] = bi0; acc1[q] = bi1; }
#pragma unroll
        for (int q = 0; q < 8; q++) {
            const float4* x4 = (const float4*)&y1s[sg*8 + q][0];
#pragma unroll
            for (int c4 = 0; c4 < 16; c4++) {
                float4 v = x4[c4];
                acc0[q] += v.x * wA[4*c4+0]; acc1[q] += v.x * wB[4*c4+0];
                acc0[q] += v.y * wA[4*c4+1]; acc1[q] += v.y * wB[4*c4+1];
                acc0[q] += v.z * wA[4*c4+2]; acc1[q] += v.z * wB[4*c4+2];
                acc0[q] += v.w * wA[4*c4+3]; acc1[q] += v.w * wB[4*c4+3];
            }
        }
#pragma unroll
        for (int q = 0; q < 8; q++) {
            ls0 += acc0[q]; lq0 += acc0[q]*acc0[q];
            ls1 += acc1[q]; lq1 += acc1[q]*acc1[q];
        }
        // per-center (zmax,zmin) -> in-place zbuf[blk*2048 + 0..255]
        {
            float* zt = zbuf + (size_t)(blk0 + e) * 2048;
            float m0 = acc0[0], n0 = acc0[0], m1 = acc1[0], n1 = acc1[0];
#pragma unroll
            for (int q = 1; q < 8; q++) {
                m0 = acc0[q] > m0 ? acc0[q] : m0;  n0 = acc0[q] < n0 ? acc0[q] : n0;
                m1 = acc1[q] > m1 ? acc1[q] : m1;  n1 = acc1[q] < n1 ? acc1[q] : n1;
            }
            rmx[d0][sg] = m0; rmn[d0][sg] = n0;
            rmx[d0+1][sg] = m1; rmn[d0+1][sg] = n1;
            __syncthreads();                 // minmax ready
            if (t < 128) {
                float mx = rmx[t][0], mn = rmn[t][0];
#pragma unroll
                for (int j = 1; j < 4; j++) {
                    mx = rmx[t][j] > mx ? rmx[t][j] : mx;
                    mn = rmn[t][j] < mn ? rmn[t][j] : mn;
                }
                zt[t] = mx;
                zt[128 + t] = mn;
            }
        }
        zc0 = zn0; zc1 = zn1;
    }
    rsum[d0][sg] = ls0; rsq[d0][sg] = lq0;
    rsum[d0+1][sg] = ls1; rsq[d0+1][sg] = lq1;
    __syncthreads();
    if (t < 128) {
        float s = 0.f, s2 = 0.f;
#pragma unroll
        for (int j = 0; j < 4; j++) { s += rsum[t][j]; s2 += rsq[t][j]; }
        float* sb = stats + (size_t)(blockIdx.x & (NBUCK-1)) * 512;
        atomicAdd(&sb[256 + t], s);
        atomicAdd(&sb[384 + t], s2);
    }
}

// S4m: out[cen][d] = relu(a * (a>0 ? zmax : zmin) + c) — bit-exact vs
// max over samples (monotonicity). Reads mm from zbuf in-place.
__global__ __launch_bounds__(256) void mlpS4m_kernel(
    const float* __restrict__ zbuf,
    const float* __restrict__ g2, const float* __restrict__ be2,
    const float* __restrict__ stats, float* __restrict__ out_feat) {
    __shared__ float lc[256];
    int blk = blockIdx.x, t = threadIdx.x;
    const float inv_n = 1.0f / (float)NTOT;
    if (t < 128) {
        float s = 0.f, s2 = 0.f;
        for (int j = 0; j < NBUCK; j++) { s += stats[j*512 + 256 + t]; s2 += stats[j*512 + 384 + t]; }
        float mean = s * inv_n, var = s2 * inv_n - mean * mean;
        float a = g2[t] * (1.0f / sqrtf(var + 1e-5f));
        lc[t] = a; lc[128 + t] = be2[t] - mean * a;
    }
    __syncthreads();
    size_t base = (size_t)blk * 4096;
    for (int i = t; i < 4096; i += 256) {
        size_t gi = base + i;
        int cen = (int)(gi >> 7), d = (int)(gi & 127);
        float a = lc[d], c = lc[128 + d];
        float z = (a > 0.f) ? zbuf[(size_t)cen*2048 + d] : zbuf[(size_t)cen*2048 + 128 + d];
        float v = a * z + c;
        out_feat[gi] = v > 0.f ? v : 0.f;
    }
}

extern "C" void kernel_launch(void* const* d_in, const int* in_sizes, int n_in,
                              void* d_out, int out_size, void* d_ws, size_t ws_size,
                              hipStream_t stream) {
    const float* xyz  = (const float*)d_in[0];
    const float* feat = (const float*)d_in[1];
    const float* w0 = (const float*)d_in[2];  const float* b0 = (const float*)d_in[3];
    const float* g0 = (const float*)d_in[4];  const float* be0 = (const float*)d_in[5];
    const float* w1 = (const float*)d_in[6];  const float* b1 = (const float*)d_in[7];
    const float* g1 = (const float*)d_in[8];  const float* be1 = (const float*)d_in[9];
    const float* w2 = (const float*)d_in[10]; const float* b2 = (const float*)d_in[11];
    const float* g2 = (const float*)d_in[12]; const float* be2 = (const float*)d_in[13];
    float* out_xyz  = (float*)d_out;
    float* out_feat = out_xyz + B_*M_*3;

    int* fps_i  = (int*)d_ws;                                   // 64 KB
    int* ball_i = (int*)((char*)d_ws + 65536);                  // 2 MB
    float* stats = (float*)((char*)d_ws + 65536 + 2097152);     // 32 KB
    size_t zoff = 65536 + 2097152 + (size_t)NBUCK*512*4;
    float* zbuf = (float*)((char*)d_ws + zoff);                 // 128 MB (proven fits, round 6)

    hipMemsetAsync(stats, 0, NBUCK*512*sizeof(float), stream);
    fps_kernel<<<B_, FPS_T, 0, stream>>>(xyz, fps_i, out_xyz);
    ballq_kernel<<<B_ * (M_/BQ_G), 256, 0, stream>>>(xyz, fps_i, ball_i);
    mlpS1_kernel<<<(B_*M_)/MCEN, 256, 0, stream>>>(xyz, feat, fps_i, ball_i, w0, b0, zbuf, stats);
    mlpS2_kernel<<<(B_*M_)/MCEN, 256, 0, stream>>>(zbuf, w1, b1, g0, be0, stats);
    mlpS3_kernel<<<(B_*M_)/MCEN, 256, 0, stream>>>(zbuf, w2, b2, g1, be1, stats);
    mlpS4m_kernel<<<512, 256, 0, stream>>>(zbuf, g2, be2, stats, out_feat);
}